// Round 4
// baseline (2447.911 us; speedup 1.0000x reference)
//
#include <hip/hip_runtime.h>
#include <stdint.h>
#include <math.h>

#define BATCH 16384
#define DIN   784
#define HID   4096
#define DOUT  10
#define KW    128            // HID/32 words per row
#define BN_EPS 1e-5

// ---------------- workspace layout (bytes) ----------------
constexpr size_t SZ_BITS   = (size_t)BATCH * KW * 4;     // 8 MB
constexpr size_t OFF_BITS1 = 0;
constexpr size_t OFF_BITS2 = OFF_BITS1 + SZ_BITS;
constexpr size_t OFF_W2B   = OFF_BITS2 + SZ_BITS;
constexpr size_t OFF_W3B   = OFF_W2B + (size_t)HID * KW * 4;
constexpr size_t OFF_W4B   = OFF_W3B + (size_t)HID * KW * 4;

// binarize a row-major fp32 matrix into bitmask words (bit e of word t = sign(w[32t+e]))
__global__ __launch_bounds__(256) void binarize_kernel(
    const float* __restrict__ w, uint32_t* __restrict__ bits, int nwords) {
  int t = blockIdx.x * 256 + threadIdx.x;
  if (t >= nwords) return;
  const float* p = w + (size_t)t * 32;
  uint32_t word = 0;
#pragma unroll
  for (int q = 0; q < 8; ++q) {
    float4 v = *(const float4*)(p + q * 4);
    word |= (uint32_t)(v.x >= 0.f) << (4 * q + 0);
    word |= (uint32_t)(v.y >= 0.f) << (4 * q + 1);
    word |= (uint32_t)(v.z >= 0.f) << (4 * q + 2);
    word |= (uint32_t)(v.w >= 0.f) << (4 * q + 3);
  }
  bits[t] = word;
}

// Layer 1: C = X(16384x784) * sign(W1)^T (4096x784), fp32 tile GEMM.
// CRITICAL SEMANTICS: per output element, accumulate k = 0..783 STRICTLY
// SEQUENTIALLY with a single f32 FMA chain. Products x*(+-1) are exact, so any
// sequential-ascending-k f32 implementation (numpy BLAS, XLA CPU) produces
// bit-identical h1 -> identical sign bits. No fixup, no f64: the reference's
// borderline signs ARE the f32-chain signs.
__global__ __launch_bounds__(256) void gemm1_kernel(
    const float* __restrict__ X, const float* __restrict__ W,
    const float* __restrict__ Bv, const float* __restrict__ Gv,
    const float* __restrict__ BEv, const float* __restrict__ Mv,
    const float* __restrict__ Vv, uint32_t* __restrict__ bits_out) {
  __shared__ float As[16 * 128];
  __shared__ float Bs[16 * 128];
  __shared__ unsigned int PW[128 * 4];   // 128 rows x 4 words (u32 bitmask)

  const int tid = threadIdx.x;
  const int bid = blockIdx.x;
  // supertile: 8 col-blocks x 128 row-blocks per group (keeps W1 slice in L2)
  const int grp = bid >> 10;
  const int rem = bid & 1023;
  const int cb  = (grp << 3) + (rem & 7);
  const int rb  = rem >> 3;
  const int m0 = rb * 128, n0 = cb * 128;
  const int tx = tid & 15, ty = tid >> 4;

  float acc[8][8];
#pragma unroll
  for (int r = 0; r < 8; ++r)
#pragma unroll
    for (int c = 0; c < 8; ++c) acc[r][c] = 0.f;

  const int sr = tid >> 1;        // staging row 0..127
  const int sk = (tid & 1) * 8;   // staging k base {0,8}
  const float* xrow = X + (size_t)(m0 + sr) * DIN + sk;
  const float* wrow = W + (size_t)(n0 + sr) * DIN + sk;

  for (int k0 = 0; k0 < DIN; k0 += 16) {   // 784 = 49 * 16, no remainder
    float4 a0 = *(const float4*)(xrow + k0);
    float4 a1 = *(const float4*)(xrow + k0 + 4);
    float4 b0 = *(const float4*)(wrow + k0);
    float4 b1 = *(const float4*)(wrow + k0 + 4);
    __syncthreads();
    As[(sk + 0) * 128 + sr] = a0.x;  As[(sk + 1) * 128 + sr] = a0.y;
    As[(sk + 2) * 128 + sr] = a0.z;  As[(sk + 3) * 128 + sr] = a0.w;
    As[(sk + 4) * 128 + sr] = a1.x;  As[(sk + 5) * 128 + sr] = a1.y;
    As[(sk + 6) * 128 + sr] = a1.z;  As[(sk + 7) * 128 + sr] = a1.w;
    Bs[(sk + 0) * 128 + sr] = (b0.x >= 0.f) ? 1.f : -1.f;
    Bs[(sk + 1) * 128 + sr] = (b0.y >= 0.f) ? 1.f : -1.f;
    Bs[(sk + 2) * 128 + sr] = (b0.z >= 0.f) ? 1.f : -1.f;
    Bs[(sk + 3) * 128 + sr] = (b0.w >= 0.f) ? 1.f : -1.f;
    Bs[(sk + 4) * 128 + sr] = (b1.x >= 0.f) ? 1.f : -1.f;
    Bs[(sk + 5) * 128 + sr] = (b1.y >= 0.f) ? 1.f : -1.f;
    Bs[(sk + 6) * 128 + sr] = (b1.z >= 0.f) ? 1.f : -1.f;
    Bs[(sk + 7) * 128 + sr] = (b1.w >= 0.f) ? 1.f : -1.f;
    __syncthreads();
#pragma unroll
    for (int kk = 0; kk < 16; ++kk) {      // ascending k within slab
      float a[8], b[8];
      *(float4*)&a[0] = *(const float4*)&As[kk * 128 + ty * 8];
      *(float4*)&a[4] = *(const float4*)&As[kk * 128 + ty * 8 + 4];
      *(float4*)&b[0] = *(const float4*)&Bs[kk * 128 + tx * 8];
      *(float4*)&b[4] = *(const float4*)&Bs[kk * 128 + tx * 8 + 4];
#pragma unroll
      for (int r = 0; r < 8; ++r)
#pragma unroll
        for (int c = 0; c < 8; ++c)
          acc[r][c] = fmaf(a[r], b[c], acc[r][c]);   // single chain per element
    }
  }

  // ---- epilogue: BN -> sign bits -> LDS atomicOr pack ----
  // be=0, m=0, g=1>0: sign(bnd) == sign(acc + b1[j]); f64 here only for tidiness.
  uint32_t bm[8];
#pragma unroll
  for (int r = 0; r < 8; ++r) bm[r] = 0;
  for (int c = 0; c < 8; ++c) {
    const int j = n0 + tx * 8 + c;
    const double scale = (double)Gv[j] / sqrt((double)Vv[j] + BN_EPS);
    const double mj = (double)Mv[j], bej = (double)BEv[j], bj = (double)Bv[j];
#pragma unroll
    for (int r = 0; r < 8; ++r) {
      // match reference order: h = acc + b (f32), then BN
      float h = acc[r][c] + (float)bj;
      double bnd = ((double)h - mj) * scale + bej;
      bm[r] |= (uint32_t)(bnd >= 0.0) << c;
    }
  }
  for (int t = tid; t < 512; t += 256) PW[t] = 0u;
  __syncthreads();
#pragma unroll
  for (int r = 0; r < 8; ++r)
    atomicOr(&PW[(ty * 8 + r) * 4 + (tx >> 2)], bm[r] << (8 * (tx & 3)));
  __syncthreads();
  for (int w = tid; w < 512; w += 256) {
    int row = w >> 2, wc = w & 3;
    bits_out[(size_t)(m0 + row) * KW + (n0 >> 5) + wc] = PW[row * 4 + wc];
  }
}

// Layers 2/3: +-1 x +-1 GEMM via XOR+popcount (exact). BN -> sign bits out.
__global__ __launch_bounds__(256) void bitgemm_kernel(
    const uint32_t* __restrict__ Abits, const uint32_t* __restrict__ Wbits,
    const float* __restrict__ Bv, const float* __restrict__ Gv,
    const float* __restrict__ BEv, const float* __restrict__ Mv,
    const float* __restrict__ Vv, uint32_t* __restrict__ bits_out) {
  __shared__ uint32_t As[16 * 128];
  __shared__ uint32_t Bs[16 * 128];
  __shared__ unsigned int PW[128 * 4];

  const int tid = threadIdx.x;
  const int cb = blockIdx.x & 31, rb = blockIdx.x >> 5;
  const int m0 = rb * 128, n0 = cb * 128;
  const int tx = tid & 15, ty = tid >> 4;

  int acc[8][8];
#pragma unroll
  for (int r = 0; r < 8; ++r)
#pragma unroll
    for (int c = 0; c < 8; ++c) acc[r][c] = 0;

  const int sr = tid >> 1;
  const int sk = (tid & 1) * 8;
  const uint32_t* arow = Abits + (size_t)(m0 + sr) * KW + sk;
  const uint32_t* wrow = Wbits + (size_t)(n0 + sr) * KW + sk;

  for (int w0 = 0; w0 < KW; w0 += 16) {
    uint4 a0 = *(const uint4*)(arow + w0);
    uint4 a1 = *(const uint4*)(arow + w0 + 4);
    uint4 b0 = *(const uint4*)(wrow + w0);
    uint4 b1 = *(const uint4*)(wrow + w0 + 4);
    __syncthreads();
    As[(sk + 0) * 128 + sr] = a0.x;  As[(sk + 1) * 128 + sr] = a0.y;
    As[(sk + 2) * 128 + sr] = a0.z;  As[(sk + 3) * 128 + sr] = a0.w;
    As[(sk + 4) * 128 + sr] = a1.x;  As[(sk + 5) * 128 + sr] = a1.y;
    As[(sk + 6) * 128 + sr] = a1.z;  As[(sk + 7) * 128 + sr] = a1.w;
    Bs[(sk + 0) * 128 + sr] = b0.x;  Bs[(sk + 1) * 128 + sr] = b0.y;
    Bs[(sk + 2) * 128 + sr] = b0.z;  Bs[(sk + 3) * 128 + sr] = b0.w;
    Bs[(sk + 4) * 128 + sr] = b1.x;  Bs[(sk + 5) * 128 + sr] = b1.y;
    Bs[(sk + 6) * 128 + sr] = b1.z;  Bs[(sk + 7) * 128 + sr] = b1.w;
    __syncthreads();
#pragma unroll
    for (int kk = 0; kk < 16; ++kk) {
      uint32_t a[8], b[8];
      *(uint4*)&a[0] = *(const uint4*)&As[kk * 128 + ty * 8];
      *(uint4*)&a[4] = *(const uint4*)&As[kk * 128 + ty * 8 + 4];
      *(uint4*)&b[0] = *(const uint4*)&Bs[kk * 128 + tx * 8];
      *(uint4*)&b[4] = *(const uint4*)&Bs[kk * 128 + tx * 8 + 4];
#pragma unroll
      for (int r = 0; r < 8; ++r)
#pragma unroll
        for (int c = 0; c < 8; ++c)
          acc[r][c] += __popc(a[r] ^ b[c]);
    }
  }

  uint32_t bm[8];
#pragma unroll
  for (int r = 0; r < 8; ++r) bm[r] = 0;
  for (int c = 0; c < 8; ++c) {
    const int j = n0 + tx * 8 + c;
    const double scale = (double)Gv[j] / sqrt((double)Vv[j] + BN_EPS);
    const double mj = (double)Mv[j], bej = (double)BEv[j], bj = (double)Bv[j];
#pragma unroll
    for (int r = 0; r < 8; ++r) {
      double h = (double)(HID - 2 * acc[r][c]) + bj;   // exact integer dot
      double bnd = (h - mj) * scale + bej;
      bm[r] |= (uint32_t)(bnd >= 0.0) << c;
    }
  }
  for (int t = tid; t < 512; t += 256) PW[t] = 0u;
  __syncthreads();
#pragma unroll
  for (int r = 0; r < 8; ++r)
    atomicOr(&PW[(ty * 8 + r) * 4 + (tx >> 2)], bm[r] << (8 * (tx & 3)));
  __syncthreads();
  for (int w = tid; w < 512; w += 256) {
    int row = w >> 2, wc = w & 3;
    bits_out[(size_t)(m0 + row) * KW + (n0 >> 5) + wc] = PW[row * 4 + wc];
  }
}

// Layer 4 (10 outputs) + log_softmax. One wave per batch row.
__global__ __launch_bounds__(256) void final_kernel(
    const uint32_t* __restrict__ xbits, const uint32_t* __restrict__ w4b,
    const float* __restrict__ b4, float* __restrict__ out) {
  __shared__ uint32_t Ws[DOUT * KW];   // 5 KB
  const int tid = threadIdx.x;
  for (int t = tid; t < DOUT * KW; t += 256) Ws[t] = w4b[t];
  __syncthreads();
  const int lane = tid & 63;
  const int i = blockIdx.x * 4 + (tid >> 6);
  const uint32_t x0 = xbits[(size_t)i * KW + lane];
  const uint32_t x1 = xbits[(size_t)i * KW + 64 + lane];
  int cnt[DOUT];
#pragma unroll
  for (int j = 0; j < DOUT; ++j)
    cnt[j] = __popc(x0 ^ Ws[j * KW + lane]) + __popc(x1 ^ Ws[j * KW + 64 + lane]);
#pragma unroll
  for (int j = 0; j < DOUT; ++j)
#pragma unroll
    for (int off = 32; off; off >>= 1) cnt[j] += __shfl_xor(cnt[j], off);
  double logit[DOUT];
  double mx = -1e300;
#pragma unroll
  for (int j = 0; j < DOUT; ++j) {
    logit[j] = (double)(HID - 2 * cnt[j]) + (double)b4[j];
    mx = fmax(mx, logit[j]);
  }
  double s = 0.0;
#pragma unroll
  for (int j = 0; j < DOUT; ++j) s += exp(logit[j] - mx);
  double lse = log(s) + mx;
  if (lane < DOUT)
    out[(size_t)i * DOUT + lane] = (float)(logit[lane] - lse);
}

extern "C" void kernel_launch(void* const* d_in, const int* in_sizes, int n_in,
                              void* d_out, int out_size, void* d_ws, size_t ws_size,
                              hipStream_t stream) {
  const float* x   = (const float*)d_in[0];
  const float* w1  = (const float*)d_in[1];
  const float* b1  = (const float*)d_in[2];
  const float* g1  = (const float*)d_in[3];
  const float* be1 = (const float*)d_in[4];
  const float* m1  = (const float*)d_in[5];
  const float* v1  = (const float*)d_in[6];
  const float* w2  = (const float*)d_in[7];
  const float* b2  = (const float*)d_in[8];
  const float* g2  = (const float*)d_in[9];
  const float* be2 = (const float*)d_in[10];
  const float* m2  = (const float*)d_in[11];
  const float* v2  = (const float*)d_in[12];
  const float* w3  = (const float*)d_in[13];
  const float* b3  = (const float*)d_in[14];
  const float* g3  = (const float*)d_in[15];
  const float* be3 = (const float*)d_in[16];
  const float* m3  = (const float*)d_in[17];
  const float* v3  = (const float*)d_in[18];
  const float* w4  = (const float*)d_in[19];
  const float* b4  = (const float*)d_in[20];

  char* ws = (char*)d_ws;
  uint32_t* bits1 = (uint32_t*)(ws + OFF_BITS1);
  uint32_t* bits2 = (uint32_t*)(ws + OFF_BITS2);
  uint32_t* w2b   = (uint32_t*)(ws + OFF_W2B);
  uint32_t* w3b   = (uint32_t*)(ws + OFF_W3B);
  uint32_t* w4b   = (uint32_t*)(ws + OFF_W4B);
  float*    out   = (float*)d_out;

  binarize_kernel<<<(HID * KW + 255) / 256, 256, 0, stream>>>(w2, w2b, HID * KW);
  binarize_kernel<<<(HID * KW + 255) / 256, 256, 0, stream>>>(w3, w3b, HID * KW);
  binarize_kernel<<<(DOUT * KW + 255) / 256, 256, 0, stream>>>(w4, w4b, DOUT * KW);

  gemm1_kernel<<<(BATCH / 128) * (HID / 128), 256, 0, stream>>>(
      x, w1, b1, g1, be1, m1, v1, bits1);

  bitgemm_kernel<<<(BATCH / 128) * (HID / 128), 256, 0, stream>>>(
      bits1, w2b, b2, g2, be2, m2, v2, bits2);
  bitgemm_kernel<<<(BATCH / 128) * (HID / 128), 256, 0, stream>>>(
      bits2, w3b, b3, g3, be3, m3, v3, bits1);

  final_kernel<<<BATCH / 4, 256, 0, stream>>>(bits1, w4b, b4, out);
}